// Round 1
// baseline (239.175 us; speedup 1.0000x reference)
//
#include <hip/hip_runtime.h>
#include <hip/hip_bf16.h>
#include <stdint.h>

// Problem dims
#define B_DIM 4096
#define NFEATS 2048
#define NTAGS 300
#define NTAGSP 320   // padded to multiple of 32
#define RIN 512
#define RHID 512
#define HIDD 512
#define KCAT 1536    // Wc|Cc|Uc concatenated K

typedef __attribute__((ext_vector_type(8))) short short8;
typedef __attribute__((ext_vector_type(8))) unsigned short ushort8;
typedef __attribute__((ext_vector_type(4))) float f32x4;

typedef __attribute__((address_space(3))) unsigned int lds_u32_t;
typedef __attribute__((address_space(1))) const unsigned int glb_u32_t;

__device__ __forceinline__ unsigned short f2bf(float f) {
  union { float f; unsigned u; } x; x.f = f;
  unsigned r = (x.u + 0x7fffu + ((x.u >> 16) & 1u)) >> 16;
  return (unsigned short)r;
}

__device__ __forceinline__ void gl2lds16(const void* g, void* l) {
  __builtin_amdgcn_global_load_lds((glb_u32_t*)g, (lds_u32_t*)l, 16, 0, 0);
}

// ---------------- conversion kernels ----------------

// f32 [rows][sc] -> bf16 [rows][dc], zero-pad cols >= sc. dc % 8 == 0.
__global__ void cvt_pad(const float* __restrict__ src, unsigned short* __restrict__ dst,
                        int rows, int sc, int dc) {
  int cpr = dc >> 3;
  long nch = (long)rows * cpr;
  for (long i = (long)blockIdx.x * blockDim.x + threadIdx.x; i < nch;
       i += (long)gridDim.x * blockDim.x) {
    int r = (int)(i / cpr);
    int c0 = (int)(i - (long)r * cpr) << 3;
    const float* s = src + (long)r * sc + c0;
    ushort8 v;
#pragma unroll
    for (int j = 0; j < 8; ++j) {
      float f = (c0 + j < sc) ? s[j] : 0.f;
      v[j] = f2bf(f);
    }
    *(ushort8*)(dst + (i << 3)) = v;
  }
}

// f32 src[g][K][N] -> bf16 dst[g][N][dstLd] at column offset dstOff,
// writing k in [k0, k0+32) with zero pad for k >= K. Grid: (ceil(Kpad/32), N/32, 4).
__global__ void trans_cvt(const float* __restrict__ src, unsigned short* __restrict__ dst,
                          int K, int N, int dstLd, int dstOff, long srcG, long dstG) {
  __shared__ float t[32][33];
  int g = blockIdx.z;
  const float* s = src + (long)g * srcG;
  unsigned short* d = dst + (long)g * dstG;
  int k0 = blockIdx.x * 32, n0 = blockIdx.y * 32;
  int tx = threadIdx.x, ty = threadIdx.y;
#pragma unroll
  for (int r = 0; r < 4; ++r) {
    int k = k0 + ty + r * 8;
    t[ty + r * 8][tx] = (k < K) ? s[(long)k * N + n0 + tx] : 0.f;
  }
  __syncthreads();
#pragma unroll
  for (int r = 0; r < 4; ++r) {
    int n = n0 + ty + r * 8;
    d[(long)n * dstLd + dstOff + k0 + tx] = f2bf(t[tx][ty + r * 8]);
  }
}

// ---------------- GEMM core (m97-style, 128x128 tile, BK=32) ----------------
// A: [M][K] bf16 row-major. Bt: [N][K] bf16 row-major (i.e. B transposed).
#define BM 128
#define BN 128
#define BK 32

__device__ __forceinline__ void stage_tile(const unsigned short* __restrict__ g, int ld,
                                           int rowBase, int k0, unsigned short* lds, int tid) {
#pragma unroll
  for (int j = 0; j < 2; ++j) {
    int chunk = j * 256 + tid;          // 512 chunks of 16B = 128 rows x 32 k
    int row = chunk >> 2;
    int kc = (chunk & 3) << 3;
    const unsigned short* src = g + (long)(rowBase + row) * ld + (k0 + kc);
    unsigned short* dst = lds + ((j * 256 + (tid & ~63)) << 3);  // wave-uniform base
    gl2lds16(src, dst);
  }
}

__device__ __forceinline__ void mma_tile(const unsigned short* As, const unsigned short* Bs,
                                         f32x4 acc[4][4], int wr, int wc, int lr, int lg) {
  short8 a[4], b[4];
#pragma unroll
  for (int mi = 0; mi < 4; ++mi)
    a[mi] = *(const short8*)(As + (wr + mi * 16 + lr) * BK + lg * 8);
#pragma unroll
  for (int ni = 0; ni < 4; ++ni)
    b[ni] = *(const short8*)(Bs + (wc + ni * 16 + lr) * BK + lg * 8);
#pragma unroll
  for (int mi = 0; mi < 4; ++mi)
#pragma unroll
    for (int ni = 0; ni < 4; ++ni)
      acc[mi][ni] = __builtin_amdgcn_mfma_f32_16x16x32_bf16(a[mi], b[ni], acc[mi][ni], 0, 0, 0);
}

__device__ __forceinline__ void gemm_loop(const unsigned short* __restrict__ A,
                                          const unsigned short* __restrict__ Bt, int K,
                                          int rowBase, int colBase,
                                          unsigned short* As, unsigned short* Bs,
                                          f32x4 acc[4][4], int tid, int wr, int wc, int lr, int lg) {
  for (int k0 = 0; k0 < K; k0 += BK) {
    __syncthreads();                 // protect LDS from prior iteration's readers
    stage_tile(A, K, rowBase, k0, As, tid);
    stage_tile(Bt, K, colBase, k0, Bs, tid);
    __syncthreads();                 // compiler drains vmcnt before barrier
    mma_tile(As, Bs, acc, wr, wc, lr, lg);
  }
}

// Stage 1: P[g][row][colOff+col] = bf16( (A1@B1t^T) * (A2@B2t^T) )
__global__ __launch_bounds__(256) void gemm_s1(
    const unsigned short* __restrict__ A1, const unsigned short* __restrict__ B1t, int K1,
    const unsigned short* __restrict__ A2, const unsigned short* __restrict__ B2t, int K2,
    unsigned short* __restrict__ P, int colOff) {
  __shared__ __align__(16) unsigned short As[BM * BK];
  __shared__ __align__(16) unsigned short Bs[BN * BK];
  int tid = threadIdx.x;
  int l = tid & 63, w = tid >> 6;
  int wr = (w >> 1) * 64, wc = (w & 1) * 64, lr = l & 15, lg = l >> 4;
  int g = blockIdx.z;
  int rowBase = blockIdx.x * BM, colBase = blockIdx.y * BN;

  f32x4 acc1[4][4], acc2[4][4];
#pragma unroll
  for (int mi = 0; mi < 4; ++mi)
#pragma unroll
    for (int ni = 0; ni < 4; ++ni)
#pragma unroll
      for (int r = 0; r < 4; ++r) { acc1[mi][ni][r] = 0.f; acc2[mi][ni][r] = 0.f; }

  gemm_loop(A1, B1t + (long)g * 512 * K1, K1, rowBase, colBase, As, Bs, acc1, tid, wr, wc, lr, lg);
  gemm_loop(A2, B2t + (long)g * 512 * K2, K2, rowBase, colBase, As, Bs, acc2, tid, wr, wc, lr, lg);

  unsigned short* Pg = P + (long)g * B_DIM * KCAT;
#pragma unroll
  for (int mi = 0; mi < 4; ++mi)
#pragma unroll
    for (int ni = 0; ni < 4; ++ni) {
      int col = colOff + colBase + wc + ni * 16 + lr;
#pragma unroll
      for (int r = 0; r < 4; ++r) {
        int row = rowBase + wr + mi * 16 + lg * 4 + r;
        float pv = acc1[mi][ni][r] * acc2[mi][ni][r];
        Pg[(long)row * KCAT + col] = f2bf(pv);
      }
    }
}

// Stage 2: logits[g][row][col] = Pcat[g] @ WcatT[g]^T + b[g][col]   (f32 out)
__global__ __launch_bounds__(256) void gemm_s2(
    const unsigned short* __restrict__ P, const unsigned short* __restrict__ WcT,
    const float* __restrict__ bias, float* __restrict__ logits) {
  __shared__ __align__(16) unsigned short As[BM * BK];
  __shared__ __align__(16) unsigned short Bs[BN * BK];
  int tid = threadIdx.x;
  int l = tid & 63, w = tid >> 6;
  int wr = (w >> 1) * 64, wc = (w & 1) * 64, lr = l & 15, lg = l >> 4;
  int g = blockIdx.z;
  int rowBase = blockIdx.x * BM, colBase = blockIdx.y * BN;

  f32x4 acc[4][4];
#pragma unroll
  for (int mi = 0; mi < 4; ++mi)
#pragma unroll
    for (int ni = 0; ni < 4; ++ni)
#pragma unroll
      for (int r = 0; r < 4; ++r) acc[mi][ni][r] = 0.f;

  gemm_loop(P + (long)g * B_DIM * KCAT, WcT + (long)g * 512 * KCAT, KCAT,
            rowBase, colBase, As, Bs, acc, tid, wr, wc, lr, lg);

  const float* bg = bias + g * HIDD;
  float* Lg = logits + (long)g * B_DIM * HIDD;
#pragma unroll
  for (int mi = 0; mi < 4; ++mi)
#pragma unroll
    for (int ni = 0; ni < 4; ++ni) {
      int col = colBase + wc + ni * 16 + lr;
      float bv = bg[col];
#pragma unroll
      for (int r = 0; r < 4; ++r) {
        int row = rowBase + wr + mi * 16 + lg * 4 + r;
        Lg[(long)row * HIDD + col] = acc[mi][ni][r] + bv;
      }
    }
}

// ---------------- final LSTM pointwise ----------------
__global__ void lstm_final(const float* __restrict__ logits, const float* __restrict__ c_in,
                           float* __restrict__ out) {
  const long GS = (long)B_DIM * HIDD;
  long i = (long)blockIdx.x * blockDim.x + threadIdx.x;   // over GS/4
  if (i >= (GS >> 2)) return;
  f32x4 l0 = *(const f32x4*)(logits + 4 * i);
  f32x4 l1 = *(const f32x4*)(logits + GS + 4 * i);
  f32x4 l2 = *(const f32x4*)(logits + 2 * GS + 4 * i);
  f32x4 l3 = *(const f32x4*)(logits + 3 * GS + 4 * i);
  f32x4 cv = *(const f32x4*)(c_in + 4 * i);
  f32x4 ho, co;
#pragma unroll
  for (int r = 0; r < 4; ++r) {
    float ig = 1.f / (1.f + __expf(-l0[r]));
    float fg = 1.f / (1.f + __expf(-l1[r]));
    float og = 1.f / (1.f + __expf(-l2[r]));
    float gg = tanhf(l3[r]);
    float c = fg * cv[r] + ig * gg;
    co[r] = c;
    ho[r] = og * tanhf(c);
  }
  *(f32x4*)(out + 4 * i) = ho;
  *(f32x4*)(out + GS + 4 * i) = co;
}

// ---------------- launch ----------------
extern "C" void kernel_launch(void* const* d_in, const int* in_sizes, int n_in,
                              void* d_out, int out_size, void* d_ws, size_t ws_size,
                              hipStream_t stream) {
  const float* v  = (const float*)d_in[0];
  const float* s  = (const float*)d_in[1];
  const float* x  = (const float*)d_in[2];
  const float* h  = (const float*)d_in[3];
  const float* c  = (const float*)d_in[4];
  const float* Wa = (const float*)d_in[5];
  const float* Wb = (const float*)d_in[6];
  const float* Wc = (const float*)d_in[7];
  const float* Ua = (const float*)d_in[8];
  const float* Ub = (const float*)d_in[9];
  const float* Uc = (const float*)d_in[10];
  const float* Ca = (const float*)d_in[11];
  const float* Cb = (const float*)d_in[12];
  const float* Cc = (const float*)d_in[13];
  const float* bb = (const float*)d_in[14];
  float* out = (float*)d_out;

  char* ws = (char*)d_ws;
  size_t off = 0;
  auto alloc = [&](size_t bytes) {
    char* p = ws + off;
    off = (off + bytes + 255) & ~(size_t)255;
    return p;
  };
  unsigned short* vb    = (unsigned short*)alloc((size_t)B_DIM * NFEATS * 2);
  unsigned short* sb    = (unsigned short*)alloc((size_t)B_DIM * NTAGSP * 2);
  unsigned short* xb    = (unsigned short*)alloc((size_t)B_DIM * RIN * 2);
  unsigned short* hb    = (unsigned short*)alloc((size_t)B_DIM * RHID * 2);
  unsigned short* WaT   = (unsigned short*)alloc((size_t)4 * 512 * 512 * 2);
  unsigned short* WbT   = (unsigned short*)alloc((size_t)4 * 512 * NTAGSP * 2);
  unsigned short* UaT   = (unsigned short*)alloc((size_t)4 * 512 * 512 * 2);
  unsigned short* UbT   = (unsigned short*)alloc((size_t)4 * 512 * NTAGSP * 2);
  unsigned short* CaT   = (unsigned short*)alloc((size_t)4 * 512 * NFEATS * 2);
  unsigned short* CbT   = (unsigned short*)alloc((size_t)4 * 512 * NTAGSP * 2);
  unsigned short* WcatT = (unsigned short*)alloc((size_t)4 * 512 * KCAT * 2);
  unsigned short* Pbuf  = (unsigned short*)alloc((size_t)4 * B_DIM * KCAT * 2);
  float*          Lg    = (float*)alloc((size_t)4 * B_DIM * HIDD * 4);

  // activation converts (bf16, pad s to 320 cols)
  cvt_pad<<<2048, 256, 0, stream>>>(v, vb, B_DIM, NFEATS, NFEATS);
  cvt_pad<<<1024, 256, 0, stream>>>(x, xb, B_DIM, RIN, RIN);
  cvt_pad<<<1024, 256, 0, stream>>>(h, hb, B_DIM, RHID, RHID);
  cvt_pad<<<640, 256, 0, stream>>>(s, sb, B_DIM, NTAGS, NTAGSP);

  // weight transposes -> [g][N=512][Kpad] bf16
  dim3 tb(32, 8);
  trans_cvt<<<dim3(16, 16, 4), tb, 0, stream>>>(Wa, WaT, 512, 512, 512, 0, (long)512 * 512, (long)512 * 512);
  trans_cvt<<<dim3(10, 16, 4), tb, 0, stream>>>(Wb, WbT, 300, 512, NTAGSP, 0, (long)300 * 512, (long)512 * NTAGSP);
  trans_cvt<<<dim3(16, 16, 4), tb, 0, stream>>>(Ua, UaT, 512, 512, 512, 0, (long)512 * 512, (long)512 * 512);
  trans_cvt<<<dim3(10, 16, 4), tb, 0, stream>>>(Ub, UbT, 300, 512, NTAGSP, 0, (long)300 * 512, (long)512 * NTAGSP);
  trans_cvt<<<dim3(64, 16, 4), tb, 0, stream>>>(Ca, CaT, 2048, 512, 2048, 0, (long)2048 * 512, (long)512 * 2048);
  trans_cvt<<<dim3(10, 16, 4), tb, 0, stream>>>(Cb, CbT, 300, 512, NTAGSP, 0, (long)300 * 512, (long)512 * NTAGSP);
  trans_cvt<<<dim3(16, 16, 4), tb, 0, stream>>>(Wc, WcatT, 512, 512, KCAT, 0, (long)512 * 512, (long)512 * KCAT);
  trans_cvt<<<dim3(16, 16, 4), tb, 0, stream>>>(Cc, WcatT, 512, 512, KCAT, 512, (long)512 * 512, (long)512 * KCAT);
  trans_cvt<<<dim3(16, 16, 4), tb, 0, stream>>>(Uc, WcatT, 512, 512, KCAT, 1024, (long)512 * 512, (long)512 * KCAT);

  // stage-1 fused bilinear products -> P[g][B][1536] bf16
  dim3 gg(B_DIM / BM, 512 / BN, 4);
  gemm_s1<<<gg, 256, 0, stream>>>(xb, WaT, 512, sb, WbT, NTAGSP, Pbuf, 0);      // (x@Wa)*(s@Wb)
  gemm_s1<<<gg, 256, 0, stream>>>(vb, CaT, NFEATS, sb, CbT, NTAGSP, Pbuf, 512); // (v@Ca)*(s@Cb)
  gemm_s1<<<gg, 256, 0, stream>>>(hb, UaT, 512, sb, UbT, NTAGSP, Pbuf, 1024);   // (h@Ua)*(s@Ub)

  // stage-2: logits = Pcat @ Wcat + b
  gemm_s2<<<gg, 256, 0, stream>>>(Pbuf, WcatT, bb, Lg);

  // final LSTM pointwise -> out = [new_h | new_c]
  lstm_final<<<(B_DIM * HIDD / 4 + 255) / 256, 256, 0, stream>>>(Lg, c, out);
}

// Round 2
// 200.724 us; speedup vs baseline: 1.1916x; 1.1916x over previous
//
#include <hip/hip_runtime.h>
#include <hip/hip_bf16.h>
#include <stdint.h>

// Problem dims
#define B_DIM 4096
#define NFEATS 2048
#define NTAGS 300
#define NTAGSP 320   // padded to multiple of 32
#define RIN 512
#define RHID 512
#define HIDD 512
#define KCAT 1536    // Wc|Cc|Uc concatenated K
#define NGATE_N 2048 // 4 gates x 512 folded into N

typedef __attribute__((ext_vector_type(8))) short short8;
typedef __attribute__((ext_vector_type(8))) unsigned short ushort8;
typedef __attribute__((ext_vector_type(4))) float f32x4;

typedef __attribute__((address_space(3))) unsigned int lds_u32_t;
typedef __attribute__((address_space(1))) const unsigned int glb_u32_t;

__device__ __forceinline__ unsigned short f2bf(float f) {
  union { float f; unsigned u; } x; x.f = f;
  unsigned r = (x.u + 0x7fffu + ((x.u >> 16) & 1u)) >> 16;
  return (unsigned short)r;
}

__device__ __forceinline__ void gl2lds16(const void* g, void* l) {
  __builtin_amdgcn_global_load_lds((glb_u32_t*)g, (lds_u32_t*)l, 16, 0, 0);
}

// ---------------- merged activation convert ----------------
// blockIdx.y selects tensor: 0=v 1=x 2=h 3=s (s pads 300->320 cols)
__global__ void cvt_all(const float* __restrict__ v, const float* __restrict__ x,
                        const float* __restrict__ h, const float* __restrict__ s,
                        unsigned short* __restrict__ vb, unsigned short* __restrict__ xb,
                        unsigned short* __restrict__ hb, unsigned short* __restrict__ sb) {
  int seg = blockIdx.y;
  const float* src; unsigned short* dst; int sc, dc;
  if (seg == 0)      { src = v; dst = vb; sc = NFEATS; dc = NFEATS; }
  else if (seg == 1) { src = x; dst = xb; sc = RIN;    dc = RIN; }
  else if (seg == 2) { src = h; dst = hb; sc = RHID;   dc = RHID; }
  else               { src = s; dst = sb; sc = NTAGS;  dc = NTAGSP; }
  int cpr = dc >> 3;
  long nch = (long)B_DIM * cpr;
  for (long i = (long)blockIdx.x * blockDim.x + threadIdx.x; i < nch;
       i += (long)gridDim.x * blockDim.x) {
    int r = (int)(i / cpr);
    int c0 = (int)(i - (long)r * cpr) << 3;
    const float* sp = src + (long)r * sc + c0;
    ushort8 o;
#pragma unroll
    for (int j = 0; j < 8; ++j) {
      float f = (c0 + j < sc) ? sp[j] : 0.f;
      o[j] = f2bf(f);
    }
    *(ushort8*)(dst + (i << 3)) = o;
  }
}

// ---------------- merged weight transpose-convert ----------------
// f32 src[g][K][512] -> bf16 dst[g][512][dstLd] at col offset dstOff, zero-pad k>=K.
struct TD { const float* src; unsigned short* dst; int K; int dstLd; int dstOff; int kx0; };
struct TP { TD d[9]; };

__global__ void trans_all(TP tp) {
  __shared__ float t[32][33];
  int bx = blockIdx.x;
  int m = 0;
#pragma unroll
  for (int i = 1; i < 9; ++i)
    if (bx >= tp.d[i].kx0) m = i;
  TD td = tp.d[m];
  int g = blockIdx.z;
  const float* s = td.src + (long)g * td.K * 512;
  unsigned short* d = td.dst + (long)g * 512 * td.dstLd;
  int k0 = (bx - td.kx0) * 32, n0 = blockIdx.y * 32;
  int tx = threadIdx.x, ty = threadIdx.y;
#pragma unroll
  for (int r = 0; r < 4; ++r) {
    int k = k0 + ty + r * 8;
    t[ty + r * 8][tx] = (k < td.K) ? s[(long)k * 512 + n0 + tx] : 0.f;
  }
  __syncthreads();
#pragma unroll
  for (int r = 0; r < 4; ++r) {
    int n = n0 + ty + r * 8;
    d[(long)n * td.dstLd + td.dstOff + k0 + tx] = f2bf(t[tx][ty + r * 8]);
  }
}

// ---------------- GEMM core (m97-style, 128x128 tile, BK=32) ----------------
#define BM 128
#define BN 128
#define BK 32

__device__ __forceinline__ void stage_tile(const unsigned short* __restrict__ g, int ld,
                                           int rowBase, int k0, unsigned short* lds, int tid) {
#pragma unroll
  for (int j = 0; j < 2; ++j) {
    int chunk = j * 256 + tid;          // 512 chunks of 16B = 128 rows x 32 k
    int row = chunk >> 2;
    int kc = (chunk & 3) << 3;
    const unsigned short* src = g + (long)(rowBase + row) * ld + (k0 + kc);
    unsigned short* dst = lds + ((j * 256 + (tid & ~63)) << 3);  // wave-uniform base
    gl2lds16(src, dst);
  }
}

__device__ __forceinline__ void mma_tile(const unsigned short* As, const unsigned short* Bs,
                                         f32x4 acc[4][4], int wr, int wc, int lr, int lg) {
  short8 a[4], b[4];
#pragma unroll
  for (int mi = 0; mi < 4; ++mi)
    a[mi] = *(const short8*)(As + (wr + mi * 16 + lr) * BK + lg * 8);
#pragma unroll
  for (int ni = 0; ni < 4; ++ni)
    b[ni] = *(const short8*)(Bs + (wc + ni * 16 + lr) * BK + lg * 8);
#pragma unroll
  for (int mi = 0; mi < 4; ++mi)
#pragma unroll
    for (int ni = 0; ni < 4; ++ni)
      acc[mi][ni] = __builtin_amdgcn_mfma_f32_16x16x32_bf16(a[mi], b[ni], acc[mi][ni], 0, 0, 0);
}

__device__ __forceinline__ void gemm_loop(const unsigned short* __restrict__ A,
                                          const unsigned short* __restrict__ Bt, int K,
                                          int rowBase, int colBase,
                                          unsigned short* As, unsigned short* Bs,
                                          f32x4 acc[4][4], int tid, int wr, int wc, int lr, int lg) {
  for (int k0 = 0; k0 < K; k0 += BK) {
    __syncthreads();                 // protect LDS from prior iteration's readers
    stage_tile(A, K, rowBase, k0, As, tid);
    stage_tile(Bt, K, colBase, k0, Bs, tid);
    __syncthreads();                 // drains vmcnt before barrier
    mma_tile(As, Bs, acc, wr, wc, lr, lg);
  }
}

// Stage 1 merged: z selects source branch; gates folded into N (Bt viewed [2048][K]).
// z=0: (v@Ca)*(s@Cb) -> P col 512..1023
// z=1: (x@Wa)*(s@Wb) -> P col 0..511
// z=2: (h@Ua)*(s@Ub) -> P col 1024..1535
__global__ __launch_bounds__(256) void gemm_s1_all(
    const unsigned short* __restrict__ vb, const unsigned short* __restrict__ xb,
    const unsigned short* __restrict__ hb, const unsigned short* __restrict__ sb,
    const unsigned short* __restrict__ CaT, const unsigned short* __restrict__ WaT,
    const unsigned short* __restrict__ UaT,
    const unsigned short* __restrict__ CbT, const unsigned short* __restrict__ WbT,
    const unsigned short* __restrict__ UbT,
    unsigned short* __restrict__ P) {
  __shared__ __align__(16) unsigned short As[BM * BK];
  __shared__ __align__(16) unsigned short Bs[BN * BK];
  int z = blockIdx.z;
  const unsigned short *A1, *B1t, *B2t;
  int K1, coff;
  if (z == 0)      { A1 = vb; B1t = CaT; K1 = NFEATS; B2t = CbT; coff = 512; }
  else if (z == 1) { A1 = xb; B1t = WaT; K1 = RIN;    B2t = WbT; coff = 0; }
  else             { A1 = hb; B1t = UaT; K1 = RHID;   B2t = UbT; coff = 1024; }

  int tid = threadIdx.x;
  int l = tid & 63, w = tid >> 6;
  int wr = (w >> 1) * 64, wc = (w & 1) * 64, lr = l & 15, lg = l >> 4;
  int rowBase = blockIdx.x * BM, colBase = blockIdx.y * BN;  // colBase in [0,2048)

  f32x4 acc1[4][4], acc2[4][4];
#pragma unroll
  for (int mi = 0; mi < 4; ++mi)
#pragma unroll
    for (int ni = 0; ni < 4; ++ni)
#pragma unroll
      for (int r = 0; r < 4; ++r) { acc1[mi][ni][r] = 0.f; acc2[mi][ni][r] = 0.f; }

  gemm_loop(A1, B1t, K1, rowBase, colBase, As, Bs, acc1, tid, wr, wc, lr, lg);
  gemm_loop(sb, B2t, NTAGSP, rowBase, colBase, As, Bs, acc2, tid, wr, wc, lr, lg);

  int gate = colBase >> 9;                 // uniform per block (BN=128 divides 512)
  unsigned short* Pg = P + (long)gate * B_DIM * KCAT;
#pragma unroll
  for (int mi = 0; mi < 4; ++mi)
#pragma unroll
    for (int ni = 0; ni < 4; ++ni) {
      int colg = colBase + wc + ni * 16 + lr;
      int col = coff + (colg & 511);
#pragma unroll
      for (int r = 0; r < 4; ++r) {
        int row = rowBase + wr + mi * 16 + lg * 4 + r;
        float pv = acc1[mi][ni][r] * acc2[mi][ni][r];
        Pg[(long)row * KCAT + col] = f2bf(pv);
      }
    }
}

// Stage 2: logits[g][row][col] = Pcat[g] @ WcatT[g]^T + b[g][col]   (f32 out)
__global__ __launch_bounds__(256) void gemm_s2(
    const unsigned short* __restrict__ P, const unsigned short* __restrict__ WcT,
    const float* __restrict__ bias, float* __restrict__ logits) {
  __shared__ __align__(16) unsigned short As[BM * BK];
  __shared__ __align__(16) unsigned short Bs[BN * BK];
  int tid = threadIdx.x;
  int l = tid & 63, w = tid >> 6;
  int wr = (w >> 1) * 64, wc = (w & 1) * 64, lr = l & 15, lg = l >> 4;
  int g = blockIdx.z;
  int rowBase = blockIdx.x * BM, colBase = blockIdx.y * BN;

  f32x4 acc[4][4];
#pragma unroll
  for (int mi = 0; mi < 4; ++mi)
#pragma unroll
    for (int ni = 0; ni < 4; ++ni)
#pragma unroll
      for (int r = 0; r < 4; ++r) acc[mi][ni][r] = 0.f;

  gemm_loop(P + (long)g * B_DIM * KCAT, WcT + (long)g * 512 * KCAT, KCAT,
            rowBase, colBase, As, Bs, acc, tid, wr, wc, lr, lg);

  const float* bg = bias + g * HIDD;
  float* Lg = logits + (long)g * B_DIM * HIDD;
#pragma unroll
  for (int mi = 0; mi < 4; ++mi)
#pragma unroll
    for (int ni = 0; ni < 4; ++ni) {
      int col = colBase + wc + ni * 16 + lr;
      float bv = bg[col];
#pragma unroll
      for (int r = 0; r < 4; ++r) {
        int row = rowBase + wr + mi * 16 + lg * 4 + r;
        Lg[(long)row * HIDD + col] = acc[mi][ni][r] + bv;
      }
    }
}

// ---------------- final LSTM pointwise ----------------
__global__ void lstm_final(const float* __restrict__ logits, const float* __restrict__ c_in,
                           float* __restrict__ out) {
  const long GS = (long)B_DIM * HIDD;
  long i = (long)blockIdx.x * blockDim.x + threadIdx.x;   // over GS/4
  if (i >= (GS >> 2)) return;
  f32x4 l0 = *(const f32x4*)(logits + 4 * i);
  f32x4 l1 = *(const f32x4*)(logits + GS + 4 * i);
  f32x4 l2 = *(const f32x4*)(logits + 2 * GS + 4 * i);
  f32x4 l3 = *(const f32x4*)(logits + 3 * GS + 4 * i);
  f32x4 cv = *(const f32x4*)(c_in + 4 * i);
  f32x4 ho, co;
#pragma unroll
  for (int r = 0; r < 4; ++r) {
    float ig = 1.f / (1.f + __expf(-l0[r]));
    float fg = 1.f / (1.f + __expf(-l1[r]));
    float og = 1.f / (1.f + __expf(-l2[r]));
    float gg = tanhf(l3[r]);
    float c = fg * cv[r] + ig * gg;
    co[r] = c;
    ho[r] = og * tanhf(c);
  }
  *(f32x4*)(out + 4 * i) = ho;
  *(f32x4*)(out + GS + 4 * i) = co;
}

// ---------------- launch ----------------
extern "C" void kernel_launch(void* const* d_in, const int* in_sizes, int n_in,
                              void* d_out, int out_size, void* d_ws, size_t ws_size,
                              hipStream_t stream) {
  const float* v  = (const float*)d_in[0];
  const float* s  = (const float*)d_in[1];
  const float* x  = (const float*)d_in[2];
  const float* h  = (const float*)d_in[3];
  const float* c  = (const float*)d_in[4];
  const float* Wa = (const float*)d_in[5];
  const float* Wb = (const float*)d_in[6];
  const float* Wc = (const float*)d_in[7];
  const float* Ua = (const float*)d_in[8];
  const float* Ub = (const float*)d_in[9];
  const float* Uc = (const float*)d_in[10];
  const float* Ca = (const float*)d_in[11];
  const float* Cb = (const float*)d_in[12];
  const float* Cc = (const float*)d_in[13];
  const float* bb = (const float*)d_in[14];
  float* out = (float*)d_out;

  char* ws = (char*)d_ws;
  size_t off = 0;
  auto alloc = [&](size_t bytes) {
    char* p = ws + off;
    off = (off + bytes + 255) & ~(size_t)255;
    return p;
  };
  unsigned short* vb    = (unsigned short*)alloc((size_t)B_DIM * NFEATS * 2);
  unsigned short* sb    = (unsigned short*)alloc((size_t)B_DIM * NTAGSP * 2);
  unsigned short* xb    = (unsigned short*)alloc((size_t)B_DIM * RIN * 2);
  unsigned short* hb    = (unsigned short*)alloc((size_t)B_DIM * RHID * 2);
  unsigned short* WaT   = (unsigned short*)alloc((size_t)4 * 512 * 512 * 2);
  unsigned short* WbT   = (unsigned short*)alloc((size_t)4 * 512 * NTAGSP * 2);
  unsigned short* UaT   = (unsigned short*)alloc((size_t)4 * 512 * 512 * 2);
  unsigned short* UbT   = (unsigned short*)alloc((size_t)4 * 512 * NTAGSP * 2);
  unsigned short* CaT   = (unsigned short*)alloc((size_t)4 * 512 * NFEATS * 2);
  unsigned short* CbT   = (unsigned short*)alloc((size_t)4 * 512 * NTAGSP * 2);
  unsigned short* WcatT = (unsigned short*)alloc((size_t)4 * 512 * KCAT * 2);
  unsigned short* Pbuf  = (unsigned short*)alloc((size_t)4 * B_DIM * KCAT * 2);
  float*          Lg    = (float*)alloc((size_t)4 * B_DIM * HIDD * 4);

  // 1) merged activation converts
  cvt_all<<<dim3(512, 4), 256, 0, stream>>>(v, x, h, s, vb, xb, hb, sb);

  // 2) merged weight transposes (prefix table over kx blocks)
  TP tp;
  tp.d[0] = { Wa, WaT,   512, 512,  0,    0   };
  tp.d[1] = { Wb, WbT,   300, 320,  0,    16  };
  tp.d[2] = { Ua, UaT,   512, 512,  0,    26  };
  tp.d[3] = { Ub, UbT,   300, 320,  0,    42  };
  tp.d[4] = { Ca, CaT,  2048, 2048, 0,    52  };
  tp.d[5] = { Cb, CbT,   300, 320,  0,    116 };
  tp.d[6] = { Wc, WcatT, 512, 1536, 0,    126 };
  tp.d[7] = { Cc, WcatT, 512, 1536, 512,  142 };
  tp.d[8] = { Uc, WcatT, 512, 1536, 1024, 158 };
  trans_all<<<dim3(174, 16, 4), dim3(32, 8), 0, stream>>>(tp);

  // 3) merged stage-1 bilinear GEMMs (gates folded into N; z = source)
  gemm_s1_all<<<dim3(B_DIM / BM, NGATE_N / BN, 3), 256, 0, stream>>>(
      vb, xb, hb, sb, CaT, WaT, UaT, CbT, WbT, UbT, Pbuf);

  // 4) stage-2: logits = Pcat @ Wcat + b
  gemm_s2<<<dim3(B_DIM / BM, HIDD / BN, 4), 256, 0, stream>>>(Pbuf, WcatT, bb, Lg);

  // 5) final LSTM pointwise -> out = [new_h | new_c]
  lstm_final<<<(B_DIM * HIDD / 4 + 255) / 256, 256, 0, stream>>>(Lg, c, out);
}

// Round 5
// 197.881 us; speedup vs baseline: 1.2087x; 1.0144x over previous
//
#include <hip/hip_runtime.h>
#include <hip/hip_bf16.h>
#include <stdint.h>

// Problem dims
#define B_DIM 4096
#define NFEATS 2048
#define NTAGS 300
#define NTAGSP 320
#define RIN 512
#define RHID 512
#define HIDD 512
#define KCAT 1536

typedef __attribute__((ext_vector_type(8))) short short8;
typedef __attribute__((ext_vector_type(8))) unsigned short ushort8;
typedef __attribute__((ext_vector_type(4))) float f32x4;

typedef __attribute__((address_space(3))) unsigned int lds_u32_t;
typedef __attribute__((address_space(1))) const unsigned int glb_u32_t;

__device__ __forceinline__ unsigned short f2bf(float f) {
  union { float f; unsigned u; } x; x.f = f;
  unsigned r = (x.u + 0x7fffu + ((x.u >> 16) & 1u)) >> 16;
  return (unsigned short)r;
}
__device__ __forceinline__ float bf2f(unsigned short u) {
  union { unsigned u; float f; } x; x.u = ((unsigned)u) << 16;
  return x.f;
}

__device__ __forceinline__ void gl2lds16(const void* g, void* l) {
  __builtin_amdgcn_global_load_lds((glb_u32_t*)g, (lds_u32_t*)l, 16, 0, 0);
}

__device__ __forceinline__ void sbar() {
  asm volatile("" ::: "memory");
  __builtin_amdgcn_s_barrier();
  asm volatile("" ::: "memory");
}
#define VMCNT4()   asm volatile("s_waitcnt vmcnt(4)" ::: "memory")
#define VMCNT0()   asm volatile("s_waitcnt vmcnt(0)" ::: "memory")
#define LGKMCNT0() asm volatile("s_waitcnt lgkmcnt(0)" ::: "memory")

// ---------------- merged activation convert ----------------
__global__ void cvt_all(const float* __restrict__ v, const float* __restrict__ x,
                        const float* __restrict__ h, const float* __restrict__ s,
                        unsigned short* __restrict__ vb, unsigned short* __restrict__ xb,
                        unsigned short* __restrict__ hb, unsigned short* __restrict__ sb) {
  int seg = blockIdx.y;
  const float* src; unsigned short* dst; int sc, dc;
  if (seg == 0)      { src = v; dst = vb; sc = NFEATS; dc = NFEATS; }
  else if (seg == 1) { src = x; dst = xb; sc = RIN;    dc = RIN; }
  else if (seg == 2) { src = h; dst = hb; sc = RHID;   dc = RHID; }
  else               { src = s; dst = sb; sc = NTAGS;  dc = NTAGSP; }
  int cpr = dc >> 3;
  long nch = (long)B_DIM * cpr;
  for (long i = (long)blockIdx.x * blockDim.x + threadIdx.x; i < nch;
       i += (long)gridDim.x * blockDim.x) {
    int r = (int)(i / cpr);
    int c0 = (int)(i - (long)r * cpr) << 3;
    const float* sp = src + (long)r * sc + c0;
    ushort8 o;
#pragma unroll
    for (int j = 0; j < 8; ++j) {
      float f = (c0 + j < sc) ? sp[j] : 0.f;
      o[j] = f2bf(f);
    }
    *(ushort8*)(dst + (i << 3)) = o;
  }
}

// ---------------- merged weight transpose-convert ----------------
struct TD { const float* src; unsigned short* dst; int K; int dstLd; int dstOff; int kx0; };
struct TP { TD d[9]; };

__global__ void trans_all(TP tp) {
  __shared__ float t[32][33];
  int bx = blockIdx.x;
  int m = 0;
#pragma unroll
  for (int i = 1; i < 9; ++i)
    if (bx >= tp.d[i].kx0) m = i;
  TD td = tp.d[m];
  int g = blockIdx.z;
  const float* s = td.src + (long)g * td.K * 512;
  unsigned short* d = td.dst + (long)g * 512 * td.dstLd;
  int k0 = (bx - td.kx0) * 32, n0 = blockIdx.y * 32;
  int tx = threadIdx.x, ty = threadIdx.y;
#pragma unroll
  for (int r = 0; r < 4; ++r) {
    int k = k0 + ty + r * 8;
    t[ty + r * 8][tx] = (k < td.K) ? s[(long)k * 512 + n0 + tx] : 0.f;
  }
  __syncthreads();
#pragma unroll
  for (int r = 0; r < 4; ++r) {
    int n = n0 + ty + r * 8;
    d[(long)n * td.dstLd + td.dstOff + k0 + tx] = f2bf(t[tx][ty + r * 8]);
  }
}

// ================= 256x256 8-phase GEMM core =================
// (unchanged from round 4 — deterministic-verified; see round-4 notes)

__device__ __forceinline__ void stage_half(const unsigned short* mat, int ld,
                                           int gRow0, int k0, char* ldsHalf,
                                           int rl0, int scb, int dstoff) {
  const char* s0 = (const char*)(mat + (long)(gRow0 + rl0) * ld + k0) + scb;
  const char* s1 = (const char*)(mat + (long)(gRow0 + 64 + rl0) * ld + k0) + scb;
  gl2lds16(s0, ldsHalf + dstoff);
  gl2lds16(s1, ldsHalf + 8192 + dstoff);
}

__device__ __forceinline__ void mfma_q(f32x4 (&acc)[8][4], int mb, int nb,
                                       const short8 (&af)[4][2], const short8 (&bf)[2][2]) {
  __builtin_amdgcn_s_setprio(1);
#pragma unroll
  for (int m = 0; m < 4; ++m)
#pragma unroll
    for (int n = 0; n < 2; ++n)
#pragma unroll
      for (int kk = 0; kk < 2; ++kk)
        acc[mb + m][nb + n] =
            __builtin_amdgcn_mfma_f32_16x16x32_bf16(af[m][kk], bf[n][kk], acc[mb + m][nb + n], 0, 0, 0);
  __builtin_amdgcn_s_setprio(0);
}

__device__ __forceinline__ void gemm8_core(const unsigned short* __restrict__ A, int lda,
                                           const unsigned short* __restrict__ Bm, int ldb,
                                           int nt, int rowBase, int colBase,
                                           char* smem, int tid, f32x4 (&acc)[8][4]) {
  char* Ab0 = smem;
  char* Bb0 = smem + 65536;
  int l = tid & 63, w = tid >> 6;
  int wr = w >> 2, wc = w & 3;
  int lr = l & 15, lg = l >> 4;
  int LA = lr * 128 + ((lg * 16) ^ ((lr & 7) << 4));   // swizzled lane read base
  int rl0 = tid >> 3;
  int scb = ((tid & 7) << 4) ^ ((rl0 & 7) << 4);       // inverse-swizzled src col
  int dstoff = (tid & ~63) << 4;                       // wave-uniform LDS base

#pragma unroll
  for (int mi = 0; mi < 8; ++mi)
#pragma unroll
    for (int ni = 0; ni < 4; ++ni)
#pragma unroll
      for (int r = 0; r < 4; ++r) acc[mi][ni][r] = 0.f;

  // prologue: tile0 A+B -> buf0; tile1 A -> buf1. Leaves A(1)x4 outstanding.
  stage_half(A, lda, rowBase, 0, Ab0, rl0, scb, dstoff);
  stage_half(A, lda, rowBase + 128, 0, Ab0 + 16384, rl0, scb, dstoff);
  stage_half(Bm, ldb, colBase, 0, Bb0, rl0, scb, dstoff);
  stage_half(Bm, ldb, colBase + 128, 0, Bb0 + 16384, rl0, scb, dstoff);
  if (nt > 1) {
    stage_half(A, lda, rowBase, 64, Ab0 + 32768, rl0, scb, dstoff);
    stage_half(A, lda, rowBase + 128, 64, Ab0 + 49152, rl0, scb, dstoff);
    VMCNT4();
  } else {
    VMCNT0();
  }
  sbar();

  for (int g = 0; g < nt; ++g) {
    int cur = g & 1;
    char* Ab = Ab0 + cur * 32768 + wr * 16384;
    char* Bb = Bb0 + cur * 32768 + wc * 8192;
    char* BbN = Bb0 + (cur ^ 1) * 32768;
    short8 a[4][2], b0[2][2], b1[2][2];

    // ---- P1: read a(h0) + b0; stage B(g+1) h0 -> other buf
#pragma unroll
    for (int m = 0; m < 4; ++m) {
      a[m][0] = *(const short8*)(Ab + m * 2048 + LA);
      a[m][1] = *(const short8*)(Ab + m * 2048 + (LA ^ 64));
    }
#pragma unroll
    for (int n = 0; n < 2; ++n) {
      b0[n][0] = *(const short8*)(Bb + n * 2048 + LA);
      b0[n][1] = *(const short8*)(Bb + n * 2048 + (LA ^ 64));
    }
    if (g + 1 < nt) stage_half(Bm, ldb, colBase, (g + 1) * 64, BbN, rl0, scb, dstoff);
    sbar();
    LGKMCNT0();                 // pin: reads drained before phase-end barrier
    mfma_q(acc, 0, 0, a, b0);   // Q(0,0)
    sbar();

    // ---- P2: read b1; stage B(g+1) h1; Q(0,2) uses a(h0) x b1
#pragma unroll
    for (int n = 0; n < 2; ++n) {
      b1[n][0] = *(const short8*)(Bb + 4096 + n * 2048 + LA);
      b1[n][1] = *(const short8*)(Bb + 4096 + n * 2048 + (LA ^ 64));
    }
    if (g + 1 < nt) stage_half(Bm, ldb, colBase + 128, (g + 1) * 64, BbN + 16384, rl0, scb, dstoff);
    sbar();
    LGKMCNT0();
    mfma_q(acc, 0, 2, a, b1);
    sbar();

    // ---- P3: reload a <- A(h1); Q(4,2) uses a(h1) x b1
#pragma unroll
    for (int m = 0; m < 4; ++m) {
      a[m][0] = *(const short8*)(Ab + 8192 + m * 2048 + LA);
      a[m][1] = *(const short8*)(Ab + 8192 + m * 2048 + (LA ^ 64));
    }
    sbar();
    LGKMCNT0();
    mfma_q(acc, 4, 2, a, b1);
    sbar();

    // ---- P4: stage A(g+2) both halves -> A[cur]; Q(4,0); counted vmcnt
    if (g + 2 < nt) {
      stage_half(A, lda, rowBase, (g + 2) * 64, Ab0 + cur * 32768, rl0, scb, dstoff);
      stage_half(A, lda, rowBase + 128, (g + 2) * 64, Ab0 + cur * 32768 + 16384, rl0, scb, dstoff);
    }
    mfma_q(acc, 4, 0, a, b0);
    if (g + 2 < nt) { VMCNT4(); } else if (g + 1 < nt) { VMCNT0(); }
    sbar();
  }
}

// ---------------- GEMM kernels ----------------

// TS = s @ [Cb|Wb|Ub]^T  -> TS[3][4096][2048] bf16  (N=6144, K=320)
__global__ __launch_bounds__(512, 2) void gemm_ts(const unsigned short* __restrict__ sb,
                                                  const unsigned short* __restrict__ SBT,
                                                  unsigned short* __restrict__ TS) {
  extern __shared__ char smem[];
  int tid = threadIdx.x;
  int rowBase = blockIdx.x * 256, colBase = blockIdx.y * 256;
  f32x4 acc[8][4];
  gemm8_core(sb, NTAGSP, SBT, NTAGSP, 5, rowBase, colBase, smem, tid, acc);

  int l = tid & 63, w = tid >> 6, wr = w >> 2, wc = w & 3, lr = l & 15, lg = l >> 4;
  int branch = colBase >> 11;
  unsigned short* TSb = TS + (long)branch * B_DIM * 2048;
#pragma unroll
  for (int mi = 0; mi < 8; ++mi)
#pragma unroll
    for (int ni = 0; ni < 4; ++ni) {
      int colg = (colBase & 2047) + wc * 64 + ni * 16 + lr;
      int row0 = rowBase + wr * 128 + mi * 16 + lg * 4;
#pragma unroll
      for (int r = 0; r < 4; ++r)
        TSb[(long)(row0 + r) * 2048 + colg] = f2bf(acc[mi][ni][r]);
    }
}

// P = (A1 @ B1^T) * TS. y: 0-7 z0(v,K2048), 8-15 z1(x,K512), 16-23 z2(h,K512)
__global__ __launch_bounds__(512, 2) void gemm_bil(
    const unsigned short* __restrict__ vb, const unsigned short* __restrict__ xb,
    const unsigned short* __restrict__ hb,
    const unsigned short* __restrict__ CaT, const unsigned short* __restrict__ WaT,
    const unsigned short* __restrict__ UaT,
    const unsigned short* __restrict__ TS, unsigned short* __restrict__ P) {
  extern __shared__ char smem[];
  int tid = threadIdx.x;
  int z = blockIdx.y >> 3;
  int rowBase = blockIdx.x * 256, colBase = (blockIdx.y & 7) * 256;
  const unsigned short *A1, *B1;
  int K1, nt, coff;
  if (z == 0)      { A1 = vb; B1 = CaT; K1 = NFEATS; nt = 32; coff = 512; }
  else if (z == 1) { A1 = xb; B1 = WaT; K1 = RIN;    nt = 8;  coff = 0; }
  else             { A1 = hb; B1 = UaT; K1 = RHID;   nt = 8;  coff = 1024; }

  f32x4 acc[8][4];
  gemm8_core(A1, K1, B1, K1, nt, rowBase, colBase, smem, tid, acc);

  int l = tid & 63, w = tid >> 6, wr = w >> 2, wc = w & 3, lr = l & 15, lg = l >> 4;
  const unsigned short* TSz = TS + (long)z * B_DIM * 2048;
#pragma unroll
  for (int mi = 0; mi < 8; ++mi)
#pragma unroll
    for (int ni = 0; ni < 4; ++ni) {
      int colg = colBase + wc * 64 + ni * 16 + lr;
      int gate = colg >> 9;
      int col = coff + (colg & 511);
      int row0 = rowBase + wr * 128 + mi * 16 + lg * 4;
      unsigned short* Pg = P + (long)gate * B_DIM * KCAT;
#pragma unroll
      for (int r = 0; r < 4; ++r) {
        float ts = bf2f(TSz[(long)(row0 + r) * 2048 + colg]);
        Pg[(long)(row0 + r) * KCAT + col] = f2bf(acc[mi][ni][r] * ts);
      }
    }
}

// logits[g] = P[g] @ Wcat[g]^T + b[g]   (z = gate; FIX: per-gate A operand)
__global__ __launch_bounds__(512, 2) void gemm_lg(const unsigned short* __restrict__ P,
                                                  const unsigned short* __restrict__ WcT,
                                                  const float* __restrict__ bias,
                                                  float* __restrict__ logits) {
  extern __shared__ char smem[];
  int tid = threadIdx.x;
  int gate = blockIdx.z;
  int rowBase = blockIdx.x * 256, colBase = blockIdx.y * 256;  // colBase in [0,512)
  const unsigned short* Pg  = P + (long)gate * B_DIM * KCAT;
  const unsigned short* Wg  = WcT + (long)gate * 512 * KCAT;
  f32x4 acc[8][4];
  gemm8_core(Pg, KCAT, Wg, KCAT, 24, rowBase, colBase, smem, tid, acc);

  int l = tid & 63, w = tid >> 6, wr = w >> 2, wc = w & 3, lr = l & 15, lg = l >> 4;
  float* Lg = logits + (long)gate * B_DIM * HIDD;
  const float* bg = bias + gate * HIDD;
#pragma unroll
  for (int mi = 0; mi < 8; ++mi)
#pragma unroll
    for (int ni = 0; ni < 4; ++ni) {
      int col = colBase + wc * 64 + ni * 16 + lr;
      float bv = bg[col];
      int row0 = rowBase + wr * 128 + mi * 16 + lg * 4;
#pragma unroll
      for (int r = 0; r < 4; ++r)
        Lg[(long)(row0 + r) * HIDD + col] = acc[mi][ni][r] + bv;
    }
}

// ---------------- final LSTM pointwise ----------------
__global__ void lstm_final(const float* __restrict__ logits, const float* __restrict__ c_in,
                           float* __restrict__ out) {
  const long GS = (long)B_DIM * HIDD;
  long i = (long)blockIdx.x * blockDim.x + threadIdx.x;
  if (i >= (GS >> 2)) return;
  f32x4 l0 = *(const f32x4*)(logits + 4 * i);
  f32x4 l1 = *(const f32x4*)(logits + GS + 4 * i);
  f32x4 l2 = *(const f32x4*)(logits + 2 * GS + 4 * i);
  f32x4 l3 = *(const f32x4*)(logits + 3 * GS + 4 * i);
  f32x4 cv = *(const f32x4*)(c_in + 4 * i);
  f32x4 ho, co;
#pragma unroll
  for (int r = 0; r < 4; ++r) {
    float ig = 1.f / (1.f + __expf(-l0[r]));
    float fg = 1.f / (1.f + __expf(-l1[r]));
    float og = 1.f / (1.f + __expf(-l2[r]));
    float gg = tanhf(l3[r]);
    float c = fg * cv[r] + ig * gg;
    co[r] = c;
    ho[r] = og * tanhf(c);
  }
  *(f32x4*)(out + 4 * i) = ho;
  *(f32x4*)(out + GS + 4 * i) = co;
}

// ---------------- launch ----------------
extern "C" void kernel_launch(void* const* d_in, const int* in_sizes, int n_in,
                              void* d_out, int out_size, void* d_ws, size_t ws_size,
                              hipStream_t stream) {
  const float* v  = (const float*)d_in[0];
  const float* s  = (const float*)d_in[1];
  const float* x  = (const float*)d_in[2];
  const float* h  = (const float*)d_in[3];
  const float* c  = (const float*)d_in[4];
  const float* Wa = (const float*)d_in[5];
  const float* Wb = (const float*)d_in[6];
  const float* Wc = (const float*)d_in[7];
  const float* Ua = (const float*)d_in[8];
  const float* Ub = (const float*)d_in[9];
  const float* Uc = (const float*)d_in[10];
  const float* Ca = (const float*)d_in[11];
  const float* Cb = (const float*)d_in[12];
  const float* Cc = (const float*)d_in[13];
  const float* bb = (const float*)d_in[14];
  float* out = (float*)d_out;

  char* ws = (char*)d_ws;
  size_t off = 0;
  auto alloc = [&](size_t bytes) {
    char* p = ws + off;
    off = (off + bytes + 255) & ~(size_t)255;
    return p;
  };
  unsigned short* vb    = (unsigned short*)alloc((size_t)B_DIM * NFEATS * 2);
  unsigned short* sb    = (unsigned short*)alloc((size_t)B_DIM * NTAGSP * 2);
  unsigned short* xb    = (unsigned short*)alloc((size_t)B_DIM * RIN * 2);
  unsigned short* hb    = (unsigned short*)alloc((size_t)B_DIM * RHID * 2);
  unsigned short* WaT   = (unsigned short*)alloc((size_t)4 * 512 * 512 * 2);
  unsigned short* UaT   = (unsigned short*)alloc((size_t)4 * 512 * 512 * 2);
  unsigned short* CaT   = (unsigned short*)alloc((size_t)4 * 512 * NFEATS * 2);
  unsigned short* WcatT = (unsigned short*)alloc((size_t)4 * 512 * KCAT * 2);
  unsigned short* SBT   = (unsigned short*)alloc((size_t)3 * 2048 * NTAGSP * 2);   // [Cb|Wb|Ub]^T
  unsigned short* TSb   = (unsigned short*)alloc((size_t)3 * B_DIM * 2048 * 2);    // s-branch products
  unsigned short* Pbuf  = (unsigned short*)alloc((size_t)4 * B_DIM * KCAT * 2);
  float*          Lg    = (float*)TSb;  // alias: TS dead once gemm_bil completes

  // 1) activation converts
  cvt_all<<<dim3(512, 4), 256, 0, stream>>>(v, x, h, s, vb, xb, hb, sb);

  // 2) weight transposes (SBT order: Cb | Wb | Ub to match gemm_bil z order)
  TP tp;
  tp.d[0] = { Wa, WaT,                  512, 512,  0,    0   };
  tp.d[1] = { Wb, SBT + 2048 * 320,     300, 320,  0,    16  };
  tp.d[2] = { Ua, UaT,                  512, 512,  0,    26  };
  tp.d[3] = { Ub, SBT + 2 * 2048 * 320, 300, 320,  0,    42  };
  tp.d[4] = { Ca, CaT,                 2048, 2048, 0,    52  };
  tp.d[5] = { Cb, SBT,                  300, 320,  0,    116 };
  tp.d[6] = { Wc, WcatT,                512, 1536, 0,    126 };
  tp.d[7] = { Cc, WcatT,                512, 1536, 512,  142 };
  tp.d[8] = { Uc, WcatT,                512, 1536, 1024, 158 };
  trans_all<<<dim3(174, 16, 4), dim3(32, 8), 0, stream>>>(tp);

  // 3) GEMMs (256^2 8-phase, 128KB dynamic LDS)
  hipFuncSetAttribute((const void*)gemm_ts,  hipFuncAttributeMaxDynamicSharedMemorySize, 131072);
  hipFuncSetAttribute((const void*)gemm_bil, hipFuncAttributeMaxDynamicSharedMemorySize, 131072);
  hipFuncSetAttribute((const void*)gemm_lg,  hipFuncAttributeMaxDynamicSharedMemorySize, 131072);

  gemm_ts<<<dim3(16, 24), 512, 131072, stream>>>(sb, SBT, TSb);
  gemm_bil<<<dim3(16, 24), 512, 131072, stream>>>(vb, xb, hb, CaT, WaT, UaT, TSb, Pbuf);
  gemm_lg<<<dim3(16, 2, 4), 512, 131072, stream>>>(Pbuf, WcatT, bb, Lg);

  // 4) LSTM pointwise
  lstm_final<<<(B_DIM * HIDD / 4 + 255) / 256, 256, 0, stream>>>(Lg, c, out);
}

// Round 6
// 186.706 us; speedup vs baseline: 1.2810x; 1.0599x over previous
//
#include <hip/hip_runtime.h>
#include <hip/hip_bf16.h>
#include <stdint.h>

// Problem dims
#define B_DIM 4096
#define NFEATS 2048
#define NTAGS 300
#define NTAGSP 320
#define RIN 512
#define RHID 512
#define HIDD 512
#define KCAT 1536

typedef __attribute__((ext_vector_type(8))) short short8;
typedef __attribute__((ext_vector_type(8))) unsigned short ushort8;
typedef __attribute__((ext_vector_type(4))) float f32x4;

typedef __attribute__((address_space(3))) unsigned int lds_u32_t;
typedef __attribute__((address_space(1))) const unsigned int glb_u32_t;

__device__ __forceinline__ unsigned short f2bf(float f) {
  union { float f; unsigned u; } x; x.f = f;
  unsigned r = (x.u + 0x7fffu + ((x.u >> 16) & 1u)) >> 16;
  return (unsigned short)r;
}
__device__ __forceinline__ float bf2f(unsigned short u) {
  union { unsigned u; float f; } x; x.u = ((unsigned)u) << 16;
  return x.f;
}

__device__ __forceinline__ void gl2lds16(const void* g, void* l) {
  __builtin_amdgcn_global_load_lds((glb_u32_t*)g, (lds_u32_t*)l, 16, 0, 0);
}

__device__ __forceinline__ void sbar() {
  asm volatile("" ::: "memory");
  __builtin_amdgcn_s_barrier();
  asm volatile("" ::: "memory");
}
#define VMCNT4()   asm volatile("s_waitcnt vmcnt(4)" ::: "memory")
#define VMCNT2()   asm volatile("s_waitcnt vmcnt(2)" ::: "memory")
#define VMCNT0()   asm volatile("s_waitcnt vmcnt(0)" ::: "memory")
#define LGKMCNT0() asm volatile("s_waitcnt lgkmcnt(0)" ::: "memory")

// ---------------- merged activation convert ----------------
__global__ void cvt_all(const float* __restrict__ v, const float* __restrict__ x,
                        const float* __restrict__ h, const float* __restrict__ s,
                        unsigned short* __restrict__ vb, unsigned short* __restrict__ xb,
                        unsigned short* __restrict__ hb, unsigned short* __restrict__ sb) {
  int seg = blockIdx.y;
  const float* src; unsigned short* dst; int sc, dc;
  if (seg == 0)      { src = v; dst = vb; sc = NFEATS; dc = NFEATS; }
  else if (seg == 1) { src = x; dst = xb; sc = RIN;    dc = RIN; }
  else if (seg == 2) { src = h; dst = hb; sc = RHID;   dc = RHID; }
  else               { src = s; dst = sb; sc = NTAGS;  dc = NTAGSP; }
  int cpr = dc >> 3;
  long nch = (long)B_DIM * cpr;
  for (long i = (long)blockIdx.x * blockDim.x + threadIdx.x; i < nch;
       i += (long)gridDim.x * blockDim.x) {
    int r = (int)(i / cpr);
    int c0 = (int)(i - (long)r * cpr) << 3;
    const float* sp = src + (long)r * sc + c0;
    ushort8 o;
#pragma unroll
    for (int j = 0; j < 8; ++j) {
      float f = (c0 + j < sc) ? sp[j] : 0.f;
      o[j] = f2bf(f);
    }
    *(ushort8*)(dst + (i << 3)) = o;
  }
}

// ---------------- merged weight transpose-convert ----------------
struct TD { const float* src; unsigned short* dst; int K; int dstLd; int dstOff; int kx0; };
struct TP { TD d[9]; };

__global__ void trans_all(TP tp) {
  __shared__ float t[32][33];
  int bx = blockIdx.x;
  int m = 0;
#pragma unroll
  for (int i = 1; i < 9; ++i)
    if (bx >= tp.d[i].kx0) m = i;
  TD td = tp.d[m];
  int g = blockIdx.z;
  const float* s = td.src + (long)g * td.K * 512;
  unsigned short* d = td.dst + (long)g * 512 * td.dstLd;
  int k0 = (bx - td.kx0) * 32, n0 = blockIdx.y * 32;
  int tx = threadIdx.x, ty = threadIdx.y;
#pragma unroll
  for (int r = 0; r < 4; ++r) {
    int k = k0 + ty + r * 8;
    t[ty + r * 8][tx] = (k < td.K) ? s[(long)k * 512 + n0 + tx] : 0.f;
  }
  __syncthreads();
#pragma unroll
  for (int r = 0; r < 4; ++r) {
    int n = n0 + ty + r * 8;
    d[(long)n * td.dstLd + td.dstOff + k0 + tx] = f2bf(t[tx][ty + r * 8]);
  }
}

// ================= (64*MFR)x256 8-phase GEMM core =================
// MFR=4: 256x256 tile (verified round-5 core; all derived offsets reduce
// to the original constants). MFR=2: 128x256 tile, 96KB LDS, vmcnt(2).
// 512 threads = 8 waves (2M x 4N); per-wave C = 32*MFR x 64.
// T2 swizzle: logical (row,cb) at byte row*128 + (cb ^ ((row&7)<<4));
// staged linearly with inverse-swizzled global source (involution).
// Every phase pins s_waitcnt lgkmcnt(0) between its two barriers.

__device__ __forceinline__ void stage_half(const unsigned short* mat, int ld,
                                           int gRow0, int k0, char* ldsHalf,
                                           int rl0, int scb, int dstoff) {
  const char* s0 = (const char*)(mat + (long)(gRow0 + rl0) * ld + k0) + scb;
  const char* s1 = (const char*)(mat + (long)(gRow0 + 64 + rl0) * ld + k0) + scb;
  gl2lds16(s0, ldsHalf + dstoff);
  gl2lds16(s1, ldsHalf + 8192 + dstoff);
}

template<int MFR>
__device__ __forceinline__ void mfma_q(f32x4 (&acc)[2 * MFR][4], int mb, int nb,
                                       const short8 (&af)[MFR][2], const short8 (&bf)[2][2]) {
  __builtin_amdgcn_s_setprio(1);
#pragma unroll
  for (int m = 0; m < MFR; ++m)
#pragma unroll
    for (int n = 0; n < 2; ++n)
#pragma unroll
      for (int kk = 0; kk < 2; ++kk)
        acc[mb + m][nb + n] =
            __builtin_amdgcn_mfma_f32_16x16x32_bf16(af[m][kk], bf[n][kk], acc[mb + m][nb + n], 0, 0, 0);
  __builtin_amdgcn_s_setprio(0);
}

template<int MFR>
__device__ __forceinline__ void gemm8_core(const unsigned short* __restrict__ A, int lda,
                                           const unsigned short* __restrict__ Bm, int ldb,
                                           int nt, int rowBase, int colBase,
                                           char* smem, int tid, f32x4 (&acc)[2 * MFR][4]) {
  constexpr int ATILE = 8192 * MFR;     // bytes per A K-tile (64*MFR rows x 128B)
  char* Ab0 = smem;                      // A dbuf: 2*ATILE
  char* Bb0 = smem + 2 * ATILE;          // B dbuf: 2*32KB
  int l = tid & 63, w = tid >> 6;
  int wr = w >> 2, wc = w & 3;
  int lr = l & 15, lg = l >> 4;
  int LA = lr * 128 + ((lg * 16) ^ ((lr & 7) << 4));   // swizzled lane read base
  int rl0 = tid >> 3;
  int scb = ((tid & 7) << 4) ^ ((rl0 & 7) << 4);       // inverse-swizzled src col
  int dstoff = (tid & ~63) << 4;                       // wave-uniform LDS base

#pragma unroll
  for (int mi = 0; mi < 2 * MFR; ++mi)
#pragma unroll
    for (int ni = 0; ni < 4; ++ni)
#pragma unroll
      for (int r = 0; r < 4; ++r) acc[mi][ni][r] = 0.f;

  // prologue: tile0 A+B -> buf0; tile1 A -> buf1.
  stage_half(A, lda, rowBase, 0, Ab0, rl0, scb, dstoff);
  if constexpr (MFR == 4) stage_half(A, lda, rowBase + 128, 0, Ab0 + ATILE / 2, rl0, scb, dstoff);
  stage_half(Bm, ldb, colBase, 0, Bb0, rl0, scb, dstoff);
  stage_half(Bm, ldb, colBase + 128, 0, Bb0 + 16384, rl0, scb, dstoff);
  if (nt > 1) {
    stage_half(A, lda, rowBase, 64, Ab0 + ATILE, rl0, scb, dstoff);
    if constexpr (MFR == 4) stage_half(A, lda, rowBase + 128, 64, Ab0 + ATILE + ATILE / 2, rl0, scb, dstoff);
    if constexpr (MFR == 4) { VMCNT4(); } else { VMCNT2(); }
  } else {
    VMCNT0();
  }
  sbar();

  for (int g = 0; g < nt; ++g) {
    int cur = g & 1;
    char* Ab = Ab0 + cur * ATILE + wr * (ATILE / 2);
    char* Bb = Bb0 + cur * 32768 + wc * 8192;
    char* BbN = Bb0 + (cur ^ 1) * 32768;
    short8 a[MFR][2], b0[2][2], b1[2][2];

    // ---- P1: read a(group0) + b0; stage B(g+1) h0 -> other buf
#pragma unroll
    for (int m = 0; m < MFR; ++m) {
      a[m][0] = *(const short8*)(Ab + m * 2048 + LA);
      a[m][1] = *(const short8*)(Ab + m * 2048 + (LA ^ 64));
    }
#pragma unroll
    for (int n = 0; n < 2; ++n) {
      b0[n][0] = *(const short8*)(Bb + n * 2048 + LA);
      b0[n][1] = *(const short8*)(Bb + n * 2048 + (LA ^ 64));
    }
    if (g + 1 < nt) stage_half(Bm, ldb, colBase, (g + 1) * 64, BbN, rl0, scb, dstoff);
    sbar();
    LGKMCNT0();                       // pin: reads drained before phase-end barrier
    mfma_q<MFR>(acc, 0, 0, a, b0);    // Q(0,0)
    sbar();

    // ---- P2: read b1; stage B(g+1) h1; Q(0,2) uses a(group0) x b1
#pragma unroll
    for (int n = 0; n < 2; ++n) {
      b1[n][0] = *(const short8*)(Bb + 4096 + n * 2048 + LA);
      b1[n][1] = *(const short8*)(Bb + 4096 + n * 2048 + (LA ^ 64));
    }
    if (g + 1 < nt) stage_half(Bm, ldb, colBase + 128, (g + 1) * 64, BbN + 16384, rl0, scb, dstoff);
    sbar();
    LGKMCNT0();
    mfma_q<MFR>(acc, 0, 2, a, b1);
    sbar();

    // ---- P3: reload a <- A(group1); Q(MFR,2)
#pragma unroll
    for (int m = 0; m < MFR; ++m) {
      a[m][0] = *(const short8*)(Ab + ATILE / 4 + m * 2048 + LA);
      a[m][1] = *(const short8*)(Ab + ATILE / 4 + m * 2048 + (LA ^ 64));
    }
    sbar();
    LGKMCNT0();
    mfma_q<MFR>(acc, MFR, 2, a, b1);
    sbar();

    // ---- P4: stage A(g+2) -> A[cur]; Q(MFR,0); counted vmcnt
    if (g + 2 < nt) {
      stage_half(A, lda, rowBase, (g + 2) * 64, Ab0 + cur * ATILE, rl0, scb, dstoff);
      if constexpr (MFR == 4)
        stage_half(A, lda, rowBase + 128, (g + 2) * 64, Ab0 + cur * ATILE + ATILE / 2, rl0, scb, dstoff);
    }
    mfma_q<MFR>(acc, MFR, 0, a, b0);
    if (g + 2 < nt) {
      if constexpr (MFR == 4) { VMCNT4(); } else { VMCNT2(); }
    } else if (g + 1 < nt) {
      VMCNT0();
    }
    sbar();
  }
}

// ---------------- GEMM kernels ----------------

// TS = s @ [Cb|Wb|Ub]^T  -> TS[3][4096][2048] bf16  (N=6144, K=320)
__global__ __launch_bounds__(512, 2) void gemm_ts(const unsigned short* __restrict__ sb,
                                                  const unsigned short* __restrict__ SBT,
                                                  unsigned short* __restrict__ TS) {
  extern __shared__ char smem[];
  int tid = threadIdx.x;
  int rowBase = blockIdx.x * 256, colBase = blockIdx.y * 256;
  f32x4 acc[8][4];
  gemm8_core<4>(sb, NTAGSP, SBT, NTAGSP, 5, rowBase, colBase, smem, tid, acc);

  int l = tid & 63, w = tid >> 6, wr = w >> 2, wc = w & 3, lr = l & 15, lg = l >> 4;
  int branch = colBase >> 11;
  unsigned short* TSb = TS + (long)branch * B_DIM * 2048;
#pragma unroll
  for (int mi = 0; mi < 8; ++mi)
#pragma unroll
    for (int ni = 0; ni < 4; ++ni) {
      int colg = (colBase & 2047) + wc * 64 + ni * 16 + lr;
      int row0 = rowBase + wr * 128 + mi * 16 + lg * 4;
#pragma unroll
      for (int r = 0; r < 4; ++r)
        TSb[(long)(row0 + r) * 2048 + colg] = f2bf(acc[mi][ni][r]);
    }
}

// P = (A1 @ B1^T) * TS, balanced grid: 512 blocks 1-D.
// bid 0..255:  z0 (v,K2048) at 128x256 tiles (MFR=2), 32 M x 8 N
// bid 256..383: z1 (x,K512) at 256x256 (MFR=4), 16 M x 8 N
// bid 384..511: z2 (h,K512) at 256x256 (MFR=4)
__global__ __launch_bounds__(512, 2) void gemm_bil(
    const unsigned short* __restrict__ vb, const unsigned short* __restrict__ xb,
    const unsigned short* __restrict__ hb,
    const unsigned short* __restrict__ CaT, const unsigned short* __restrict__ WaT,
    const unsigned short* __restrict__ UaT,
    const unsigned short* __restrict__ TS, unsigned short* __restrict__ P) {
  extern __shared__ char smem[];
  int tid = threadIdx.x;
  int bid = blockIdx.x;
  int l = tid & 63, w = tid >> 6, wr = w >> 2, wc = w & 3, lr = l & 15, lg = l >> 4;

  if (bid < 256) {
    // z0: heavy v-path, 128x256 tiles
    int rowBase = (bid & 31) * 128, colBase = (bid >> 5) * 256;
    f32x4 acc[4][4];
    gemm8_core<2>(vb, NFEATS, CaT, NFEATS, NFEATS / 64, rowBase, colBase, smem, tid, acc);

    const unsigned short* TSz = TS;   // z = 0
#pragma unroll
    for (int mi = 0; mi < 4; ++mi)
#pragma unroll
      for (int ni = 0; ni < 4; ++ni) {
        int colg = colBase + wc * 64 + ni * 16 + lr;
        int gate = colg >> 9;
        int col = 512 + (colg & 511);
        int row0 = rowBase + wr * 64 + mi * 16 + lg * 4;
        unsigned short* Pg = P + (long)gate * B_DIM * KCAT;
#pragma unroll
        for (int r = 0; r < 4; ++r) {
          float ts = bf2f(TSz[(long)(row0 + r) * 2048 + colg]);
          Pg[(long)(row0 + r) * KCAT + col] = f2bf(acc[mi][ni][r] * ts);
        }
      }
  } else {
    int t = bid - 256;
    int z = 1 + (t >> 7); t &= 127;
    int rowBase = (t & 15) * 256, colBase = (t >> 4) * 256;
    const unsigned short* A1 = (z == 1) ? xb : hb;
    const unsigned short* B1 = (z == 1) ? WaT : UaT;
    int coff = (z == 1) ? 0 : 1024;
    f32x4 acc[8][4];
    gemm8_core<4>(A1, RIN, B1, RIN, RIN / 64, rowBase, colBase, smem, tid, acc);

    const unsigned short* TSz = TS + (long)z * B_DIM * 2048;
#pragma unroll
    for (int mi = 0; mi < 8; ++mi)
#pragma unroll
      for (int ni = 0; ni < 4; ++ni) {
        int colg = colBase + wc * 64 + ni * 16 + lr;
        int gate = colg >> 9;
        int col = coff + (colg & 511);
        int row0 = rowBase + wr * 128 + mi * 16 + lg * 4;
        unsigned short* Pg = P + (long)gate * B_DIM * KCAT;
#pragma unroll
        for (int r = 0; r < 4; ++r) {
          float ts = bf2f(TSz[(long)(row0 + r) * 2048 + colg]);
          Pg[(long)(row0 + r) * KCAT + col] = f2bf(acc[mi][ni][r] * ts);
        }
      }
  }
}

// logits[g] = P[g] @ Wcat[g]^T + b[g]   (128x256 tiles, MFR=2, 256 blocks)
__global__ __launch_bounds__(512, 2) void gemm_lg(const unsigned short* __restrict__ P,
                                                  const unsigned short* __restrict__ WcT,
                                                  const float* __restrict__ bias,
                                                  float* __restrict__ logits) {
  extern __shared__ char smem[];
  int tid = threadIdx.x;
  int gate = blockIdx.z;
  int rowBase = blockIdx.x * 128, colBase = blockIdx.y * 256;
  const unsigned short* Pg = P + (long)gate * B_DIM * KCAT;
  const unsigned short* Wg = WcT + (long)gate * 512 * KCAT;
  f32x4 acc[4][4];
  gemm8_core<2>(Pg, KCAT, Wg, KCAT, KCAT / 64, rowBase, colBase, smem, tid, acc);

  int l = tid & 63, w = tid >> 6, wr = w >> 2, wc = w & 3, lr = l & 15, lg = l >> 4;
  float* Lg = logits + (long)gate * B_DIM * HIDD;
  const float* bg = bias + gate * HIDD;
#pragma unroll
  for (int mi = 0; mi < 4; ++mi)
#pragma unroll
    for (int ni = 0; ni < 4; ++ni) {
      int col = colBase + wc * 64 + ni * 16 + lr;
      float bv = bg[col];
      int row0 = rowBase + wr * 64 + mi * 16 + lg * 4;
#pragma unroll
      for (int r = 0; r < 4; ++r)
        Lg[(long)(row0 + r) * HIDD + col] = acc[mi][ni][r] + bv;
    }
}

// ---------------- final LSTM pointwise ----------------
__global__ void lstm_final(const float* __restrict__ logits, const float* __restrict__ c_in,
                           float* __restrict__ out) {
  const long GS = (long)B_DIM * HIDD;
  long i = (long)blockIdx.x * blockDim.x + threadIdx.x;
  if (i >= (GS >> 2)) return;
  f32x4 l0 = *(const f32x4*)(logits + 4 * i);
  f32x4 l1 = *(const f32x4*)(logits + GS + 4 * i);
  f32x4 l2 = *(const f32x4*)(logits + 2 * GS + 4 * i);
  f32x4 l3 = *(const f32x4*)(logits + 3 * GS + 4 * i);
  f32x4 cv = *(const f32x4*)(c_in + 4 * i);
  f32x4 ho, co;
#pragma unroll
  for (int r = 0; r < 4; ++r) {
    float ig = 1.f / (1.f + __expf(-l0[r]));
    float fg = 1.f / (1.f + __expf(-l1[r]));
    float og = 1.f / (1.f + __expf(-l2[r]));
    float gg = tanhf(l3[r]);
    float c = fg * cv[r] + ig * gg;
    co[r] = c;
    ho[r] = og * tanhf(c);
  }
  *(f32x4*)(out + 4 * i) = ho;
  *(f32x4*)(out + GS + 4 * i) = co;
}

// ---------------- launch ----------------
extern "C" void kernel_launch(void* const* d_in, const int* in_sizes, int n_in,
                              void* d_out, int out_size, void* d_ws, size_t ws_size,
                              hipStream_t stream) {
  const float* v  = (const float*)d_in[0];
  const float* s  = (const float*)d_in[1];
  const float* x  = (const float*)d_in[2];
  const float* h  = (const float*)d_in[3];
  const float* c  = (const float*)d_in[4];
  const float* Wa = (const float*)d_in[5];
  const float* Wb = (const float*)d_in[6];
  const float* Wc = (const float*)d_in[7];
  const float* Ua = (const float*)d_in[8];
  const float* Ub = (const float*)d_in[9];
  const float* Uc = (const float*)d_in[10];
  const float* Ca = (const float*)d_in[11];
  const float* Cb = (const float*)d_in[12];
  const float* Cc = (const float*)d_in[13];
  const float* bb = (const float*)d_in[14];
  float* out = (float*)d_out;

  char* ws = (char*)d_ws;
  size_t off = 0;
  auto alloc = [&](size_t bytes) {
    char* p = ws + off;
    off = (off + bytes + 255) & ~(size_t)255;
    return p;
  };
  unsigned short* vb    = (unsigned short*)alloc((size_t)B_DIM * NFEATS * 2);
  unsigned short* sb    = (unsigned short*)alloc((size_t)B_DIM * NTAGSP * 2);
  unsigned short* xb    = (unsigned short*)alloc((size_t)B_DIM * RIN * 2);
  unsigned short* hb    = (unsigned short*)alloc((size_t)B_DIM * RHID * 2);
  unsigned short* WaT   = (unsigned short*)alloc((size_t)4 * 512 * 512 * 2);
  unsigned short* UaT   = (unsigned short*)alloc((size_t)4 * 512 * 512 * 2);
  unsigned short* CaT   = (unsigned short*)alloc((size_t)4 * 512 * NFEATS * 2);
  unsigned short* WcatT = (unsigned short*)alloc((size_t)4 * 512 * KCAT * 2);
  unsigned short* SBT   = (unsigned short*)alloc((size_t)3 * 2048 * NTAGSP * 2);   // [Cb|Wb|Ub]^T
  unsigned short* TSb   = (unsigned short*)alloc((size_t)3 * B_DIM * 2048 * 2);    // s-branch products
  unsigned short* Pbuf  = (unsigned short*)alloc((size_t)4 * B_DIM * KCAT * 2);
  float*          Lg    = (float*)TSb;  // alias: TS dead once gemm_bil completes

  // 1) activation converts
  cvt_all<<<dim3(512, 4), 256, 0, stream>>>(v, x, h, s, vb, xb, hb, sb);

  // 2) weight transposes (SBT order: Cb | Wb | Ub to match gemm_bil z order)
  TP tp;
  tp.d[0] = { Wa, WaT,                  512, 512,  0,    0   };
  tp.d[1] = { Wb, SBT + 2048 * 320,     300, 320,  0,    16  };
  tp.d[2] = { Ua, UaT,                  512, 512,  0,    26  };
  tp.d[3] = { Ub, SBT + 2 * 2048 * 320, 300, 320,  0,    42  };
  tp.d[4] = { Ca, CaT,                 2048, 2048, 0,    52  };
  tp.d[5] = { Cb, SBT,                  300, 320,  0,    116 };
  tp.d[6] = { Wc, WcatT,                512, 1536, 0,    126 };
  tp.d[7] = { Cc, WcatT,                512, 1536, 512,  142 };
  tp.d[8] = { Uc, WcatT,                512, 1536, 1024, 158 };
  trans_all<<<dim3(174, 16, 4), dim3(32, 8), 0, stream>>>(tp);

  // 3) GEMMs (8-phase cores; dynamic LDS)
  hipFuncSetAttribute((const void*)gemm_ts,  hipFuncAttributeMaxDynamicSharedMemorySize, 131072);
  hipFuncSetAttribute((const void*)gemm_bil, hipFuncAttributeMaxDynamicSharedMemorySize, 131072);
  hipFuncSetAttribute((const void*)gemm_lg,  hipFuncAttributeMaxDynamicSharedMemorySize, 98304);

  gemm_ts<<<dim3(16, 24), 512, 131072, stream>>>(sb, SBT, TSb);
  gemm_bil<<<dim3(512), 512, 131072, stream>>>(vb, xb, hb, CaT, WaT, UaT, TSb, Pbuf);
  gemm_lg<<<dim3(32, 2, 4), 512, 98304, stream>>>(Pbuf, WcatT, bb, Lg);

  // 4) LSTM pointwise
  lstm_final<<<(B_DIM * HIDD / 4 + 255) / 256, 256, 0, stream>>>(Lg, c, out);
}